// Round 1
// baseline (176.643 us; speedup 1.0000x reference)
//
#include <hip/hip_runtime.h>

// element_mars[nids, :] = node_mars[cids, :, :].sum(axis=1)
// N=500000, P=500000, C=4, B=128, E=P+1 (row 0 dummy, preserved from input)
//
// Mapping: each work item = (output row r in [0, P], q = float4-column in [0,32)).
//   r == 0   -> copy dummy row 0 from element_mars input (out must be fully
//               rewritten every launch: harness poisons d_out with 0xAA).
//   r >= 1   -> product p = r-1: gather 4 child rows (each 512B contiguous,
//               coalesced across the 32 lanes), sum, store to row nids[p].

__global__ __launch_bounds__(256) void ProdLayer_15942918602882_kernel(
    const float4* __restrict__ nm,    // node_mars  [N][32] as float4
    const float4* __restrict__ em,    // element_mars input [E][32] as float4
    const int*    __restrict__ nids,  // [P]
    const int4*   __restrict__ cids,  // [P] (C=4 packed)
    float4*       __restrict__ out,   // [E][32] as float4
    int P)
{
    int gid = blockIdx.x * blockDim.x + threadIdx.x;
    int r = gid >> 5;        // output-row item: 0..P
    int q = gid & 31;        // float4 column within the 128-float row
    if (r > P) return;

    if (r == 0) {
        // dummy row 0: pass through the element_mars input
        out[q] = em[q];
        return;
    }

    int p = r - 1;
    int4 c = cids[p];        // 4 child row indices (1-based into node_mars)
    float4 a = nm[(size_t)c.x * 32 + q];
    float4 b = nm[(size_t)c.y * 32 + q];
    float4 d = nm[(size_t)c.z * 32 + q];
    float4 e = nm[(size_t)c.w * 32 + q];

    float4 s;
    s.x = (a.x + b.x) + (d.x + e.x);
    s.y = (a.y + b.y) + (d.y + e.y);
    s.z = (a.z + b.z) + (d.z + e.z);
    s.w = (a.w + b.w) + (d.w + e.w);

    out[(size_t)nids[p] * 32 + q] = s;
}

extern "C" void kernel_launch(void* const* d_in, const int* in_sizes, int n_in,
                              void* d_out, int out_size, void* d_ws, size_t ws_size,
                              hipStream_t stream) {
    const float4* nm   = (const float4*)d_in[0];  // node_mars    [N*128] f32
    const float4* em   = (const float4*)d_in[1];  // element_mars [E*128] f32
    const int*    nids = (const int*)d_in[2];     // [P] int32
    const int4*   cids = (const int4*)d_in[3];    // [P*4] int32
    float4*       out  = (float4*)d_out;          // [E*128] f32

    const int P = in_sizes[2];                    // 500000
    const long long items = (long long)(P + 1) * 32;
    const int block = 256;
    const int grid = (int)((items + block - 1) / block);

    ProdLayer_15942918602882_kernel<<<grid, block, 0, stream>>>(
        nm, em, nids, cids, out, P);
}